// Round 18
// baseline (422.904 us; speedup 1.0000x reference)
//
#include <hip/hip_runtime.h>
#include <stdint.h>

#define B_   8
#define S_   8192
#define H_   1024
#define HQ_  256
#define CAP_ 4096
#define UCAP_ (S_-CAP_)
#define M_   (B_*CAP_)   // 32768
#define EPSB 0.012f
#define LCAP 8192

using f32x4 = __attribute__((ext_vector_type(4))) float;
using s16x8 = __attribute__((ext_vector_type(8))) short;

__device__ __forceinline__ unsigned short f2bf(float f) {
  unsigned u = __float_as_uint(f);
  u += 0x7FFF + ((u >> 16) & 1);   // RNE
  return (unsigned short)(u >> 16);
}
__device__ __forceinline__ float bf2f(unsigned short h) {
  return __uint_as_float(((unsigned)h) << 16);
}

// gelu tanh-approx via hw exp: 0.5v(1+tanh(z)) == v * sigmoid(2z)
__device__ __forceinline__ float gelu_f(float v) {
  float s = v + 0.044715f * v * v * v;
  float e = __expf(-1.5957691216057308f * s);
  return v * __builtin_amdgcn_rcpf(1.0f + e);
}

// monotonic fp32 <-> u32 key
__device__ __forceinline__ unsigned mono(float f) {
  unsigned u = __float_as_uint(f);
  return (u & 0x80000000u) ? ~u : (u | 0x80000000u);
}
__device__ __forceinline__ float unmono(unsigned k) {
  unsigned u = (k & 0x80000000u) ? (k & 0x7fffffffu) : ~k;
  return __uint_as_float(u);
}

__device__ __forceinline__ void gload_lds16(const void* g, void* l) {
  __builtin_amdgcn_global_load_lds(
      (const __attribute__((address_space(1))) void*)(uintptr_t)g,
      (__attribute__((address_space(3))) void*)(uintptr_t)l,
      16, 0, 0);
}

// in-block exact radix select: returns CAP_-th largest of srow[0..S_)
__device__ __forceinline__ float radix_select_T(
    const float* __restrict__ srow, unsigned* hist,
    unsigned* sh_b, unsigned* sh_gt, int tid) {
  unsigned prefix = 0; int plen = 0; unsigned rank = CAP_;
  #pragma unroll
  for (int round = 0; round < 3; ++round) {
    const int nb = (round < 2) ? 11 : 10;
    hist[tid] = 0; hist[tid + 1024] = 0;
    __syncthreads();
    for (int i = tid; i < S_; i += 1024) {
      unsigned k = mono(srow[i]);
      if (plen == 0 || (k >> (32 - plen)) == prefix) {
        unsigned bucket = (k << plen) >> (32 - nb);
        atomicAdd(&hist[bucket], 1u);
      }
    }
    __syncthreads();
    for (int s = 1; s < 2048; s <<= 1) {
      unsigned t0 = (tid + s < 2048) ? hist[tid + s] : 0;
      unsigned t1 = (tid + 1024 + s < 2048) ? hist[tid + 1024 + s] : 0;
      __syncthreads();
      hist[tid] += t0; hist[tid + 1024] += t1;
      __syncthreads();
    }
    #pragma unroll
    for (int h = 0; h < 2; ++h) {
      int i = tid + h * 1024;
      unsigned ge = hist[i];
      unsigned gt = (i < 2047) ? hist[i + 1] : 0;
      if (gt < rank && rank <= ge) { *sh_b = (unsigned)i; *sh_gt = gt; }
    }
    __syncthreads();
    prefix = (prefix << nb) | *sh_b;
    plen += nb;
    rank -= *sh_gt;
    __syncthreads();
  }
  return unmono(prefix);
}

// ---------------- fused prep: W1 -> w1t_hi (bf16 T) + Wl -> wlt (bf16 T) -----
__global__ __launch_bounds__(256) void prep_kernel(
    const float* __restrict__ W1, unsigned short* __restrict__ w1t_hi,
    const float* __restrict__ wl, unsigned short* __restrict__ wlt) {
  __shared__ float tile[32][33];
  const int bid = blockIdx.x;
  const int tx = threadIdx.x, ty = threadIdx.y;
  if (bid < 256) {
    int n0 = (bid & 7) * 32, k0 = (bid >> 3) * 32;
    for (int i = ty; i < 32; i += 8) tile[i][tx] = W1[(size_t)(k0 + i) * HQ_ + n0 + tx];
    __syncthreads();
    for (int i = ty; i < 32; i += 8)
      w1t_hi[(size_t)(n0 + i) * H_ + k0 + tx] = f2bf(tile[tx][i]);
  } else {
    int idx = bid - 256;
    int x0 = (idx & 31) * 32, y0 = (idx >> 5) * 32;
    for (int i = ty; i < 32; i += 8) tile[i][tx] = wl[(size_t)(y0 + i) * H_ + x0 + tx];
    __syncthreads();
    for (int i = ty; i < 32; i += 8)
      wlt[(size_t)(x0 + i) * H_ + y0 + tx] = f2bf(tile[tx][i]);
  }
}

// ---------------- Router GEMM: streaming, BM=64, 3 blocks/CU -----------------
// 256 thr / 4 waves; each wave owns a 64-col block (wc=w) of all 64 rows.
// A staged raw fp32 via gload_lds (16KB), B bf16 via gload_lds (32KB), both
// single-buffered; simple 2-barrier loop; TLP (12 waves/CU) hides drains.
__global__ __launch_bounds__(256) void router_mfma_kernel(
    const float* __restrict__ x, const unsigned short* __restrict__ w1t_hi,
    const float* __restrict__ b1, const float* __restrict__ W2,
    const float* __restrict__ b2, float* __restrict__ scores,
    float* __restrict__ rw, int* __restrict__ count) {
  __shared__ __align__(16) float Af[64 * 64];              // 16 KB
  __shared__ __align__(16) unsigned short Bs[256 * 64];    // 32 KB
  __shared__ float part[64][4];
  const int t = threadIdx.x;
  const int lane = t & 63, w = t >> 6;    // 4 waves; wave w -> n-cols w*64..
  const int m0 = blockIdx.x * 64;
  if (blockIdx.x == 0 && t == 0) *count = 0;
  const int r16 = lane & 15, ks = lane >> 4;

  // A: 4 issues/thread/K-step; fp32 chunks (16B=4 floats), 16 chunks/row
  const float* aP[4];
  int adst[4];
  #pragma unroll
  for (int u = 0; u < 4; ++u) {
    int c = u * 256 + t;
    int row = c >> 4, q = c & 15;
    int qz = q ^ (row & 15);
    aP[u] = x + (size_t)(m0 + row) * H_ + qz * 4;
    adst[u] = c * 4;
  }
  // B: 8 issues/thread/K-step; bf16 chunks (16B=8 vals), 8 chunks/row
  const unsigned short* bP[8];
  int bdst[8];
  #pragma unroll
  for (int u = 0; u < 8; ++u) {
    int c = u * 256 + t;
    int row = c >> 3, sl = c & 7;
    int slz = sl ^ (row & 7);
    bP[u] = w1t_hi + (size_t)row * H_ + slz * 8;
    bdst[u] = c * 8;
  }

  f32x4 acc[4][4];
  #pragma unroll
  for (int i = 0; i < 4; ++i)
    #pragma unroll
    for (int j = 0; j < 4; ++j) acc[i][j] = (f32x4){0.f, 0.f, 0.f, 0.f};

  for (int k0 = 0; k0 < H_; k0 += 64) {
    #pragma unroll
    for (int u = 0; u < 4; ++u) gload_lds16(aP[u] + k0, &Af[adst[u]]);
    #pragma unroll
    for (int u = 0; u < 8; ++u) gload_lds16(bP[u] + k0, &Bs[bdst[u]]);
    __syncthreads();
    s16x8 af[4][2], bfr[4][2];
    #pragma unroll
    for (int i = 0; i < 4; ++i)
      #pragma unroll
      for (int kk = 0; kk < 2; ++kk) {
        int r_ = i * 16 + r16;
        int g2 = 2 * (kk * 4 + ks);
        float4 f0 = *(const float4*)&Af[(r_ * 16 + (g2 ^ (r_ & 15))) * 4];
        float4 f1 = *(const float4*)&Af[(r_ * 16 + ((g2 + 1) ^ (r_ & 15))) * 4];
        unsigned short hh[8];
        hh[0] = f2bf(f0.x); hh[1] = f2bf(f0.y); hh[2] = f2bf(f0.z); hh[3] = f2bf(f0.w);
        hh[4] = f2bf(f1.x); hh[5] = f2bf(f1.y); hh[6] = f2bf(f1.z); hh[7] = f2bf(f1.w);
        af[i][kk] = *(s16x8*)hh;
      }
    #pragma unroll
    for (int j = 0; j < 4; ++j)
      #pragma unroll
      for (int kk = 0; kk < 2; ++kk) {
        int r_ = w * 64 + j * 16 + r16;
        bfr[j][kk] = *(const s16x8*)&Bs[r_ * 64 + ((kk * 4 + ks) ^ (r_ & 7)) * 8];
      }
    #pragma unroll
    for (int i = 0; i < 4; ++i)
      #pragma unroll
      for (int j = 0; j < 4; ++j)
        #pragma unroll
        for (int kk = 0; kk < 2; ++kk)
          acc[i][j] = __builtin_amdgcn_mfma_f32_16x16x32_bf16(
              af[i][kk], bfr[j][kk], acc[i][j], 0, 0, 0);
    __syncthreads();
  }

  // epilogue: relu(z+b1)*W2 partials, reduce over 4 wave-col-groups
  float b1v[4], w2v[4];
  #pragma unroll
  for (int j = 0; j < 4; ++j) {
    int n = w * 64 + j * 16 + r16;
    b1v[j] = b1[n]; w2v[j] = W2[n];
  }
  const int g4 = lane >> 4;
  #pragma unroll
  for (int i = 0; i < 4; ++i) {
    #pragma unroll
    for (int r = 0; r < 4; ++r) {
      float p = 0.f;
      #pragma unroll
      for (int j = 0; j < 4; ++j) {
        float h = acc[i][j][r] + b1v[j];
        h = fmaxf(h, 0.f);
        p = fmaf(h, w2v[j], p);
      }
      p += __shfl_xor(p, 1);
      p += __shfl_xor(p, 2);
      p += __shfl_xor(p, 4);
      p += __shfl_xor(p, 8);
      if (r16 == 0) part[i * 16 + g4 * 4 + r][w] = p;
    }
  }
  __syncthreads();
  if (t < 64) {
    float sc = part[t][0] + part[t][1] + part[t][2] + part[t][3] + b2[0];
    scores[m0 + t] = sc;
    rw[m0 + t] = 1.f / (1.f + expf(-sc));
  }
}

// ---------------- select + band (fused): T per row, then flag near-T tokens --
__global__ __launch_bounds__(1024) void select_band_kernel(
    const float* __restrict__ scores, int* __restrict__ list,
    int* __restrict__ count) {
  __shared__ unsigned hist[2048];
  __shared__ unsigned sh_b, sh_gt;
  const int b = blockIdx.x;
  const int tid = threadIdx.x;
  const float* srow = scores + (size_t)b * S_;
  const float T = radix_select_T(srow, hist, &sh_b, &sh_gt, tid);
  for (int i = tid; i < S_; i += 1024) {
    float s = srow[i];
    if (fabsf(s - T) <= EPSB) {
      int p = atomicAdd(count, 1);
      if (p < LCAP) list[p] = b * S_ + i;
    }
  }
}

// ---------------- exact fp32 recompute (scores + rw), 4 tokens/block ---------
__global__ __launch_bounds__(256) void recompute_kernel(
    const float* __restrict__ x, const float* __restrict__ W1,
    const float* __restrict__ b1, const float* __restrict__ W2,
    const float* __restrict__ b2, const int* __restrict__ list,
    const int* __restrict__ count, float* __restrict__ scores,
    float* __restrict__ rw) {
  __shared__ float xr[4][H_];
  __shared__ float red[4][4];
  int n = *count; if (n > LCAP) n = LCAP;
  const int j = threadIdx.x;
  for (int base = blockIdx.x * 4; base < n; base += gridDim.x * 4) {
    int nt = n - base; if (nt > 4) nt = 4;
    for (int tt = 0; tt < 4; ++tt) {
      int tok = list[base + ((tt < nt) ? tt : 0)];
      const float* xrow = x + (size_t)tok * H_;
      for (int k = j; k < H_; k += 256) xr[tt][k] = xrow[k];
    }
    __syncthreads();
    float a0 = 0.f, a1 = 0.f, a2 = 0.f, a3 = 0.f;
    for (int k = 0; k < H_; ++k) {
      float wv = W1[(size_t)k * HQ_ + j];
      a0 = fmaf(xr[0][k], wv, a0);
      a1 = fmaf(xr[1][k], wv, a1);
      a2 = fmaf(xr[2][k], wv, a2);
      a3 = fmaf(xr[3][k], wv, a3);
    }
    float aa[4] = {a0, a1, a2, a3};
    #pragma unroll
    for (int tt = 0; tt < 4; ++tt) {
      float h = fmaxf(aa[tt] + b1[j], 0.f);
      float v = h * W2[j];
      v += __shfl_xor(v, 1);  v += __shfl_xor(v, 2);  v += __shfl_xor(v, 4);
      v += __shfl_xor(v, 8);  v += __shfl_xor(v, 16); v += __shfl_xor(v, 32);
      if ((j & 63) == 0) red[tt][j >> 6] = v;
    }
    __syncthreads();
    if (j < nt) {
      int tok = list[base + j];
      float sc = red[j][0] + red[j][1] + red[j][2] + red[j][3] + b2[0];
      scores[tok] = sc;
      rw[tok] = 1.f / (1.f + expf(-sc));
    }
    __syncthreads();
  }
}

// ---------------- compact (fused radix): exact T then stable compaction ------
__global__ __launch_bounds__(1024) void compact_kernel(
    const float* __restrict__ scores, int* __restrict__ comp,
    int* __restrict__ ucomp) {
  __shared__ unsigned hist[2048];
  __shared__ unsigned sh_b, sh_gt;
  __shared__ int wc_eq[16], wc_sel[16], red[16];
  const int b = blockIdx.x;
  const float* srow = scores + (size_t)b * S_;
  const int tid = threadIdx.x, lane = tid & 63, wid = tid >> 6;
  const float T = radix_select_T(srow, hist, &sh_b, &sh_gt, tid);

  int cgt = 0;
  #pragma unroll
  for (int c = 0; c < 8; ++c) cgt += (srow[c * 1024 + tid] > T) ? 1 : 0;
  cgt += __shfl_xor(cgt, 1);  cgt += __shfl_xor(cgt, 2);  cgt += __shfl_xor(cgt, 4);
  cgt += __shfl_xor(cgt, 8);  cgt += __shfl_xor(cgt, 16); cgt += __shfl_xor(cgt, 32);
  if (lane == 0) red[wid] = cgt;
  __syncthreads();
  int cnt_gt = 0;
  #pragma unroll
  for (int i = 0; i < 16; ++i) cnt_gt += red[i];
  const int need = CAP_ - cnt_gt;

  int* crow = comp + b * CAP_;
  int* urow = ucomp + b * UCAP_;
  int sel_base = 0, unsel_base = 0, eq_base = 0;
  __syncthreads();
  for (int c = 0; c < 8; ++c) {
    int idx = c * 1024 + tid;
    float s = srow[idx];
    bool gt = s > T, eq = (s == T);
    unsigned long long meq = __ballot(eq);
    if (lane == 0) wc_eq[wid] = __popcll(meq);
    __syncthreads();
    int eq_off = eq_base, eq_tot = 0;
    #pragma unroll
    for (int w2 = 0; w2 < 16; ++w2) { if (w2 < wid) eq_off += wc_eq[w2]; eq_tot += wc_eq[w2]; }
    int eqpos = eq_off + __popcll(meq & ((1ull << lane) - 1));
    bool take = gt || (eq && eqpos < need);
    unsigned long long mt = __ballot(take);
    if (lane == 0) wc_sel[wid] = __popcll(mt);
    __syncthreads();
    int sel_off = sel_base, sel_tot = 0;
    #pragma unroll
    for (int w2 = 0; w2 < 16; ++w2) { if (w2 < wid) sel_off += wc_sel[w2]; sel_tot += wc_sel[w2]; }
    if (take) {
      crow[sel_off + __popcll(mt & ((1ull << lane) - 1))] = idx;
    } else {
      int un_off = unsel_base + wid * 64 - (sel_off - sel_base);
      urow[un_off + __popcll(~mt & ((1ull << lane) - 1))] = idx;
    }
    sel_base += sel_tot; unsel_base += 1024 - sel_tot; eq_base += eq_tot;
    __syncthreads();
  }
}

// ---------------- fused gather(selected->xg bf16) + copy(unselected->out) ----
__global__ __launch_bounds__(256) void gather_copy_kernel(
    const float* __restrict__ x, const int* __restrict__ comp,
    const int* __restrict__ ucomp, unsigned short* __restrict__ xg,
    float* __restrict__ out) {
  const int bid = blockIdx.x;
  const int tx = threadIdx.x;
  if (bid < M_) {
    int b = bid >> 12, cc = bid & (CAP_ - 1);
    int token = comp[b * CAP_ + cc];
    float4 v = ((const float4*)(x + ((size_t)(b * S_ + token)) * H_))[tx];
    ushort4 o;
    o.x = f2bf(v.x); o.y = f2bf(v.y); o.z = f2bf(v.z); o.w = f2bf(v.w);
    *(ushort4*)&xg[(size_t)bid * H_ + tx * 4] = o;
  } else {
    int i = bid - M_;
    int b = i >> 12, r = i & (UCAP_ - 1);
    int token = ucomp[b * UCAP_ + r];
    size_t row = (size_t)b * S_ + token;
    ((float4*)(out + row * H_))[tx] = ((const float4*)(x + row * H_))[tx];
  }
}

// ---------------- main GEMM: 256x256 tile, 4-phase/K-tile, counted vmcnt -----
#define ISSUE_A(P, KT, BUF) do {                                               \
    int row_ = half * 128 + (P) * 32 + rr;                                     \
    int slz_ = sl ^ (row_ & 7);                                                \
    gload_lds16(xg + (size_t)(m0 + row_) * H_ + (KT) * 64 + slz_ * 8,          \
                &As[BUF][row_ * 64 + sl * 8]);                                 \
  } while (0)
#define ISSUE_B(P, KT, BUF) do {                                               \
    int row_ = half * 128 + (P) * 32 + rr;                                     \
    int slz_ = sl ^ (row_ & 7);                                                \
    gload_lds16(wlt + (size_t)(n0 + row_) * H_ + (KT) * 64 + slz_ * 8,         \
                &Bs[BUF][row_ * 64 + sl * 8]);                                 \
  } while (0)
#define MOE_PHASE(P, ISSUE, WAITSTR) do {                                      \
    s16x8 af[2][2];                                                            \
    _Pragma("unroll")                                                          \
    for (int i = 0; i < 2; ++i)                                                \
      _Pragma("unroll")                                                        \
      for (int kk = 0; kk < 2; ++kk) {                                         \
        int r_ = wr * 128 + (2 * (P) + i) * 16 + r16;                          \
        af[i][kk] = *(const s16x8*)&As[c_][r_ * 64 + ((kk * 4 + ks) ^ (r_ & 7)) * 8]; \
      }                                                                        \
    if ((P) == 0) {                                                            \
      _Pragma("unroll")                                                        \
      for (int j = 0; j < 4; ++j)                                              \
        _Pragma("unroll")                                                      \
        for (int kk = 0; kk < 2; ++kk) {                                       \
          int r_ = wc * 64 + j * 16 + r16;                                     \
          bfr[j][kk] = *(const s16x8*)&Bs[c_][r_ * 64 + ((kk * 4 + ks) ^ (r_ & 7)) * 8]; \
        }                                                                      \
    }                                                                          \
    ISSUE                                                                      \
    __builtin_amdgcn_s_barrier();                                              \
    asm volatile("s_waitcnt lgkmcnt(0)" ::: "memory");                         \
    __builtin_amdgcn_sched_barrier(0);                                         \
    __builtin_amdgcn_s_setprio(1);                                             \
    _Pragma("unroll")                                                          \
    for (int i = 0; i < 2; ++i)                                                \
      _Pragma("unroll")                                                        \
      for (int j = 0; j < 4; ++j)                                              \
        _Pragma("unroll")                                                      \
        for (int kk = 0; kk < 2; ++kk)                                         \
          acc[2 * (P) + i][j] = __builtin_amdgcn_mfma_f32_16x16x32_bf16(       \
              af[i][kk], bfr[j][kk], acc[2 * (P) + i][j], 0, 0, 0);            \
    __builtin_amdgcn_s_setprio(0);                                             \
    __builtin_amdgcn_sched_barrier(0);                                         \
    asm volatile("s_waitcnt " WAITSTR ::: "memory");                           \
    __builtin_amdgcn_s_barrier();                                              \
    __builtin_amdgcn_sched_barrier(0);                                         \
  } while (0)

__global__ __launch_bounds__(512, 1) void moe_gemm_kernel(
    const unsigned short* __restrict__ xg, const unsigned short* __restrict__ wlt,
    const int* __restrict__ comp, float* __restrict__ out) {
  __shared__ __align__(16) unsigned short As[2][256 * 64];
  __shared__ __align__(16) unsigned short Bs[2][256 * 64];
  __shared__ int toks[256];
  const int t = threadIdx.x;
  const int lane = t & 63, w = t >> 6;
  const int bid = blockIdx.x;
  const int xcd = bid & 7, wb = bid >> 3;
  const int m0 = (xcd * 16 + (wb >> 2)) * 256;
  const int n0 = (wb & 3) * 256;
  const int bb = m0 >> 12;
  if (t < 256) toks[t] = comp[bb * CAP_ + (m0 & (CAP_ - 1)) + t];
  const int wr = w >> 2, wc = w & 3;
  const int r16 = lane & 15, ks = lane >> 4;
  const int half = t >> 8, rr = (t >> 3) & 31, sl = t & 7;

  f32x4 acc[8][4];
  #pragma unroll
  for (int i = 0; i < 8; ++i)
    #pragma unroll
    for (int j = 0; j < 4; ++j) acc[i][j] = (f32x4){0.f, 0.f, 0.f, 0.f};

  ISSUE_B(0, 0, 0); ISSUE_B(1, 0, 0); ISSUE_B(2, 0, 0); ISSUE_B(3, 0, 0);
  ISSUE_A(0, 0, 0); ISSUE_A(1, 0, 0); ISSUE_A(2, 0, 0); ISSUE_A(3, 0, 0);
  asm volatile("s_waitcnt vmcnt(3)" ::: "memory");
  __syncthreads();

  for (int kt = 0; kt < 15; ++kt) {
    const int c_ = kt & 1, nb_ = c_ ^ 1;
    const int kn = kt + 1;
    s16x8 bfr[4][2];
    MOE_PHASE(0, { ISSUE_B(0, kn, nb_); ISSUE_B(1, kn, nb_); }, "vmcnt(4)");
    MOE_PHASE(1, { ISSUE_B(2, kn, nb_); ISSUE_B(3, kn, nb_); }, "vmcnt(5)");
    MOE_PHASE(2, { ISSUE_A(0, kn, nb_); ISSUE_A(1, kn, nb_); }, "vmcnt(6)");
    MOE_PHASE(3, { ISSUE_A(2, kn, nb_); ISSUE_A(3, kn, nb_); }, "vmcnt(3)");
  }
  {
    const int c_ = 1;
    s16x8 bfr[4][2];
    MOE_PHASE(0, {;}, "vmcnt(2)");
    MOE_PHASE(1, {;}, "vmcnt(1)");
    MOE_PHASE(2, {;}, "vmcnt(0)");
    MOE_PHASE(3, {;}, "vmcnt(63)");
  }

  const int g4 = lane >> 4;
  #pragma unroll
  for (int i = 0; i < 8; ++i) {
    #pragma unroll
    for (int r = 0; r < 4; ++r) {
      int rl = wr * 128 + i * 16 + g4 * 4 + r;
      int token = toks[rl];
      float* orow = out + ((size_t)(bb * S_ + token)) * H_ + n0 + wc * 64;
      #pragma unroll
      for (int j = 0; j < 4; ++j)
        orow[j * 16 + r16] = gelu_f(acc[i][j][r]);
    }
  }
}

extern "C" void kernel_launch(void* const* d_in, const int* in_sizes, int n_in,
                              void* d_out, int out_size, void* d_ws, size_t ws_size,
                              hipStream_t stream) {
  const float* x  = (const float*)d_in[0];
  const float* W1 = (const float*)d_in[1];
  const float* b1 = (const float*)d_in[2];
  const float* W2 = (const float*)d_in[3];
  const float* b2 = (const float*)d_in[4];
  const float* Wl = (const float*)d_in[5];
  float* out = (float*)d_out;
  float* rw  = out + (size_t)B_ * S_ * H_;

  char* ws = (char*)d_ws;
  float* scores        = (float*)ws;                                 // 256 KB
  int*   comp          = (int*)(ws + (256 << 10));                   // 128 KB
  int*   count         = (int*)(ws + (384 << 10) + 256);             // 4 B
  int*   list          = (int*)(ws + (384 << 10) + 512);             // 32 KB
  int*   ucomp         = (int*)(ws + (448 << 10));                   // 128 KB
  unsigned short* wlt  = (unsigned short*)(ws + (1 << 20));          // 2 MB
  unsigned short* xg   = (unsigned short*)(ws + (3 << 20));          // 64 MB
  unsigned short* w1t_hi = xg;               // 512 KB (dead before xg written)

  hipLaunchKernelGGL(prep_kernel, dim3(1280), dim3(32, 8), 0, stream,
                     W1, w1t_hi, Wl, wlt);
  hipLaunchKernelGGL(router_mfma_kernel, dim3((B_*S_)/64), dim3(256), 0, stream,
                     x, w1t_hi, b1, W2, b2, scores, rw, count);
  hipLaunchKernelGGL(select_band_kernel, dim3(B_), dim3(1024), 0, stream,
                     scores, list, count);
  hipLaunchKernelGGL(recompute_kernel, dim3(128), dim3(256), 0, stream,
                     x, W1, b1, W2, b2, list, count, scores, rw);
  hipLaunchKernelGGL(compact_kernel, dim3(B_), dim3(1024), 0, stream,
                     scores, comp, ucomp);
  hipLaunchKernelGGL(gather_copy_kernel, dim3(M_ + B_*UCAP_), dim3(256), 0, stream,
                     x, comp, ucomp, xg, out);
  hipLaunchKernelGGL(moe_gemm_kernel, dim3((M_/256)*(H_/256)), dim3(512), 0, stream,
                     xg, wlt, comp, out);
}

// Round 19
// 418.256 us; speedup vs baseline: 1.0111x; 1.0111x over previous
//
#include <hip/hip_runtime.h>
#include <stdint.h>

#define B_   8
#define S_   8192
#define H_   1024
#define HQ_  256
#define CAP_ 4096
#define UCAP_ (S_-CAP_)
#define M_   (B_*CAP_)   // 32768
#define EPSB 0.012f
#define LCAP 8192

using f32x4 = __attribute__((ext_vector_type(4))) float;
using s16x8 = __attribute__((ext_vector_type(8))) short;

__device__ __forceinline__ unsigned short f2bf(float f) {
  unsigned u = __float_as_uint(f);
  u += 0x7FFF + ((u >> 16) & 1);   // RNE
  return (unsigned short)(u >> 16);
}
__device__ __forceinline__ float bf2f(unsigned short h) {
  return __uint_as_float(((unsigned)h) << 16);
}

// gelu tanh-approx via hw exp: 0.5v(1+tanh(z)) == v * sigmoid(2z)
__device__ __forceinline__ float gelu_f(float v) {
  float s = v + 0.044715f * v * v * v;
  float e = __expf(-1.5957691216057308f * s);
  return v * __builtin_amdgcn_rcpf(1.0f + e);
}

// monotonic fp32 <-> u32 key
__device__ __forceinline__ unsigned mono(float f) {
  unsigned u = __float_as_uint(f);
  return (u & 0x80000000u) ? ~u : (u | 0x80000000u);
}
__device__ __forceinline__ float unmono(unsigned k) {
  unsigned u = (k & 0x80000000u) ? (k & 0x7fffffffu) : ~k;
  return __uint_as_float(u);
}

__device__ __forceinline__ void gload_lds16(const void* g, void* l) {
  __builtin_amdgcn_global_load_lds(
      (const __attribute__((address_space(1))) void*)(uintptr_t)g,
      (__attribute__((address_space(3))) void*)(uintptr_t)l,
      16, 0, 0);
}

// in-block exact radix select: returns CAP_-th largest of srow[0..S_)
__device__ __forceinline__ float radix_select_T(
    const float* __restrict__ srow, unsigned* hist,
    unsigned* sh_b, unsigned* sh_gt, int tid) {
  unsigned prefix = 0; int plen = 0; unsigned rank = CAP_;
  #pragma unroll
  for (int round = 0; round < 3; ++round) {
    const int nb = (round < 2) ? 11 : 10;
    hist[tid] = 0; hist[tid + 1024] = 0;
    __syncthreads();
    for (int i = tid; i < S_; i += 1024) {
      unsigned k = mono(srow[i]);
      if (plen == 0 || (k >> (32 - plen)) == prefix) {
        unsigned bucket = (k << plen) >> (32 - nb);
        atomicAdd(&hist[bucket], 1u);
      }
    }
    __syncthreads();
    for (int s = 1; s < 2048; s <<= 1) {
      unsigned t0 = (tid + s < 2048) ? hist[tid + s] : 0;
      unsigned t1 = (tid + 1024 + s < 2048) ? hist[tid + 1024 + s] : 0;
      __syncthreads();
      hist[tid] += t0; hist[tid + 1024] += t1;
      __syncthreads();
    }
    #pragma unroll
    for (int h = 0; h < 2; ++h) {
      int i = tid + h * 1024;
      unsigned ge = hist[i];
      unsigned gt = (i < 2047) ? hist[i + 1] : 0;
      if (gt < rank && rank <= ge) { *sh_b = (unsigned)i; *sh_gt = gt; }
    }
    __syncthreads();
    prefix = (prefix << nb) | *sh_b;
    plen += nb;
    rank -= *sh_gt;
    __syncthreads();
  }
  return unmono(prefix);
}

// ---------------- fused prep: W1 -> w1t_hi (bf16 T) + Wl -> wlt (bf16 T) -----
__global__ __launch_bounds__(256) void prep_kernel(
    const float* __restrict__ W1, unsigned short* __restrict__ w1t_hi,
    const float* __restrict__ wl, unsigned short* __restrict__ wlt) {
  __shared__ float tile[32][33];
  const int bid = blockIdx.x;
  const int tx = threadIdx.x, ty = threadIdx.y;
  if (bid < 256) {
    int n0 = (bid & 7) * 32, k0 = (bid >> 3) * 32;
    for (int i = ty; i < 32; i += 8) tile[i][tx] = W1[(size_t)(k0 + i) * HQ_ + n0 + tx];
    __syncthreads();
    for (int i = ty; i < 32; i += 8)
      w1t_hi[(size_t)(n0 + i) * H_ + k0 + tx] = f2bf(tile[tx][i]);
  } else {
    int idx = bid - 256;
    int x0 = (idx & 31) * 32, y0 = (idx >> 5) * 32;
    for (int i = ty; i < 32; i += 8) tile[i][tx] = wl[(size_t)(y0 + i) * H_ + x0 + tx];
    __syncthreads();
    for (int i = ty; i < 32; i += 8)
      wlt[(size_t)(x0 + i) * H_ + y0 + tx] = f2bf(tile[tx][i]);
  }
}

// ---------------- Router GEMM: 128x256 tile, 4-phase, fp32-A in LDS ----------
// (R17 proven form, unchanged)
#define RIA(U, KT, BUF) do {                                                   \
    int c_i = (U) * 512 + t;                                                   \
    int row_ = c_i >> 4, q_ = c_i & 15;                                        \
    int qz_ = q_ ^ (row_ & 15);                                                \
    gload_lds16(x + (size_t)(m0 + row_) * H_ + (KT) * 64 + qz_ * 4,            \
                &Af[BUF][(size_t)c_i * 4]);                                    \
  } while (0)
#define RIB(U, KT, BUF) do {                                                   \
    int row_ = (U) * 64 + (t >> 3);                                            \
    int sl_ = t & 7;                                                           \
    int slz_ = sl_ ^ (row_ & 7);                                               \
    gload_lds16(w1t_hi + (size_t)row_ * H_ + (KT) * 64 + slz_ * 8,             \
                &Bs[BUF][(size_t)row_ * 64 + sl_ * 8]);                        \
  } while (0)
#define RPH(P, ISSUE, WAITCODE) do {                                           \
    s16x8 af[2];                                                               \
    _Pragma("unroll")                                                          \
    for (int kk = 0; kk < 2; ++kk) {                                           \
      int r_ = wr * 64 + (P) * 16 + r16;                                       \
      int g2 = 2 * (kk * 4 + ks);                                              \
      float4 f0 = *(const float4*)&Af[c_][((size_t)r_ * 16 + (g2 ^ (r_ & 15))) * 4];       \
      float4 f1 = *(const float4*)&Af[c_][((size_t)r_ * 16 + ((g2 + 1) ^ (r_ & 15))) * 4]; \
      unsigned short hh[8];                                                    \
      hh[0] = f2bf(f0.x); hh[1] = f2bf(f0.y); hh[2] = f2bf(f0.z); hh[3] = f2bf(f0.w); \
      hh[4] = f2bf(f1.x); hh[5] = f2bf(f1.y); hh[6] = f2bf(f1.z); hh[7] = f2bf(f1.w); \
      af[kk] = *(s16x8*)hh;                                                    \
    }                                                                          \
    if ((P) == 0) {                                                            \
      _Pragma("unroll")                                                        \
      for (int j = 0; j < 4; ++j)                                              \
        _Pragma("unroll")                                                      \
        for (int kk = 0; kk < 2; ++kk) {                                       \
          int r_ = wc * 64 + j * 16 + r16;                                     \
          bfr[j][kk] = *(const s16x8*)&Bs[c_][(size_t)r_ * 64 + ((kk * 4 + ks) ^ (r_ & 7)) * 8]; \
        }                                                                      \
    }                                                                          \
    ISSUE                                                                      \
    __builtin_amdgcn_s_barrier();                                              \
    asm volatile("s_waitcnt lgkmcnt(0)" ::: "memory");                         \
    __builtin_amdgcn_sched_barrier(0);                                         \
    __builtin_amdgcn_s_setprio(1);                                             \
    _Pragma("unroll")                                                          \
    for (int j = 0; j < 4; ++j)                                                \
      _Pragma("unroll")                                                        \
      for (int kk = 0; kk < 2; ++kk)                                           \
        acc[P][j] = __builtin_amdgcn_mfma_f32_16x16x32_bf16(                   \
            af[kk], bfr[j][kk], acc[P][j], 0, 0, 0);                           \
    __builtin_amdgcn_s_setprio(0);                                             \
    __builtin_amdgcn_sched_barrier(0);                                         \
    WAITCODE                                                                   \
    __builtin_amdgcn_s_barrier();                                              \
    __builtin_amdgcn_sched_barrier(0);                                         \
  } while (0)

__global__ __launch_bounds__(512, 1) void router_mfma_kernel(
    const float* __restrict__ x, const unsigned short* __restrict__ w1t_hi,
    const float* __restrict__ b1, const float* __restrict__ W2,
    const float* __restrict__ b2, float* __restrict__ scores,
    float* __restrict__ rw, int* __restrict__ count) {
  __shared__ __align__(16) float Af[2][128 * 64];          // fp32 A, 2x32KB
  __shared__ __align__(16) unsigned short Bs[2][256 * 64]; // bf16 B, 2x32KB
  __shared__ float part[128][4];
  const int t = threadIdx.x;
  const int lane = t & 63, w = t >> 6;
  const int m0 = blockIdx.x * 128;
  if (blockIdx.x == 0 && t == 0) *count = 0;   // reset band counter
  const int wr = w >> 2, wc = w & 3;           // 2x4 wave grid, 64x64 each
  const int r16 = lane & 15, ks = lane >> 4;

  f32x4 acc[4][4];
  #pragma unroll
  for (int i = 0; i < 4; ++i)
    #pragma unroll
    for (int j = 0; j < 4; ++j) acc[i][j] = (f32x4){0.f, 0.f, 0.f, 0.f};

  // prologue: tile 0, order = consumption order (B0-3, A0, A2, A1, A3)
  RIB(0, 0, 0); RIB(1, 0, 0); RIB(2, 0, 0); RIB(3, 0, 0);
  RIA(0, 0, 0); RIA(2, 0, 0); RIA(1, 0, 0); RIA(3, 0, 0);
  asm volatile("s_waitcnt vmcnt(2)" ::: "memory");   // B0-3 + A0,A2 landed
  __syncthreads();

  for (int kt = 0; kt < 15; ++kt) {
    const int c_ = kt & 1, nb_ = c_ ^ 1;
    const int kn = kt + 1;
    s16x8 bfr[4][2];
    RPH(0, { RIB(0, kn, nb_); RIB(1, kn, nb_); }, {});
    RPH(1, { RIB(2, kn, nb_); RIB(3, kn, nb_); },
        { asm volatile("s_waitcnt vmcnt(4)" ::: "memory"); });
    RPH(2, { RIA(0, kn, nb_); RIA(2, kn, nb_); }, {});
    RPH(3, { RIA(1, kn, nb_); RIA(3, kn, nb_); },
        { asm volatile("s_waitcnt vmcnt(2)" ::: "memory"); });
  }
  {  // kt = 15: drain
    const int c_ = 1;
    s16x8 bfr[4][2];
    RPH(0, {;}, {});
    RPH(1, {;}, { asm volatile("s_waitcnt vmcnt(0)" ::: "memory"); });
    RPH(2, {;}, {});
    RPH(3, {;}, {});
  }

  // epilogue: relu(z+b1)*W2 partials, reduce across 4 wc groups
  float b1v[4], w2v[4];
  #pragma unroll
  for (int j = 0; j < 4; ++j) {
    int n = wc * 64 + j * 16 + r16;
    b1v[j] = b1[n]; w2v[j] = W2[n];
  }
  const int g4 = lane >> 4;
  #pragma unroll
  for (int i = 0; i < 4; ++i) {
    #pragma unroll
    for (int r = 0; r < 4; ++r) {
      float p = 0.f;
      #pragma unroll
      for (int j = 0; j < 4; ++j) {
        float h = acc[i][j][r] + b1v[j];
        h = fmaxf(h, 0.f);
        p = fmaf(h, w2v[j], p);
      }
      p += __shfl_xor(p, 1);
      p += __shfl_xor(p, 2);
      p += __shfl_xor(p, 4);
      p += __shfl_xor(p, 8);
      if (r16 == 0) part[wr * 64 + i * 16 + g4 * 4 + r][wc] = p;
    }
  }
  __syncthreads();
  if (t < 128) {
    float sc = part[t][0] + part[t][1] + part[t][2] + part[t][3] + b2[0];
    scores[m0 + t] = sc;
    rw[m0 + t] = 1.f / (1.f + expf(-sc));
  }
}

// ---------------- select + band (fused): T per row, then flag near-T tokens --
__global__ __launch_bounds__(1024) void select_band_kernel(
    const float* __restrict__ scores, int* __restrict__ list,
    int* __restrict__ count) {
  __shared__ unsigned hist[2048];
  __shared__ unsigned sh_b, sh_gt;
  const int b = blockIdx.x;
  const int tid = threadIdx.x;
  const float* srow = scores + (size_t)b * S_;
  const float T = radix_select_T(srow, hist, &sh_b, &sh_gt, tid);
  for (int i = tid; i < S_; i += 1024) {
    float s = srow[i];
    if (fabsf(s - T) <= EPSB) {
      int p = atomicAdd(count, 1);
      if (p < LCAP) list[p] = b * S_ + i;
    }
  }
}

// ---------------- exact fp32 recompute (scores + rw), 4 tokens/block ---------
__global__ __launch_bounds__(256) void recompute_kernel(
    const float* __restrict__ x, const float* __restrict__ W1,
    const float* __restrict__ b1, const float* __restrict__ W2,
    const float* __restrict__ b2, const int* __restrict__ list,
    const int* __restrict__ count, float* __restrict__ scores,
    float* __restrict__ rw) {
  __shared__ float xr[4][H_];
  __shared__ float red[4][4];
  int n = *count; if (n > LCAP) n = LCAP;
  const int j = threadIdx.x;
  for (int base = blockIdx.x * 4; base < n; base += gridDim.x * 4) {
    int nt = n - base; if (nt > 4) nt = 4;
    for (int tt = 0; tt < 4; ++tt) {
      int tok = list[base + ((tt < nt) ? tt : 0)];
      const float* xrow = x + (size_t)tok * H_;
      for (int k = j; k < H_; k += 256) xr[tt][k] = xrow[k];
    }
    __syncthreads();
    float a0 = 0.f, a1 = 0.f, a2 = 0.f, a3 = 0.f;
    for (int k = 0; k < H_; ++k) {
      float wv = W1[(size_t)k * HQ_ + j];
      a0 = fmaf(xr[0][k], wv, a0);
      a1 = fmaf(xr[1][k], wv, a1);
      a2 = fmaf(xr[2][k], wv, a2);
      a3 = fmaf(xr[3][k], wv, a3);
    }
    float aa[4] = {a0, a1, a2, a3};
    #pragma unroll
    for (int tt = 0; tt < 4; ++tt) {
      float h = fmaxf(aa[tt] + b1[j], 0.f);
      float v = h * W2[j];
      v += __shfl_xor(v, 1);  v += __shfl_xor(v, 2);  v += __shfl_xor(v, 4);
      v += __shfl_xor(v, 8);  v += __shfl_xor(v, 16); v += __shfl_xor(v, 32);
      if ((j & 63) == 0) red[tt][j >> 6] = v;
    }
    __syncthreads();
    if (j < nt) {
      int tok = list[base + j];
      float sc = red[j][0] + red[j][1] + red[j][2] + red[j][3] + b2[0];
      scores[tok] = sc;
      rw[tok] = 1.f / (1.f + expf(-sc));
    }
    __syncthreads();
  }
}

// ---------------- compact (fused radix): exact T then stable compaction ------
__global__ __launch_bounds__(1024) void compact_kernel(
    const float* __restrict__ scores, int* __restrict__ comp,
    int* __restrict__ ucomp) {
  __shared__ unsigned hist[2048];
  __shared__ unsigned sh_b, sh_gt;
  __shared__ int wc_eq[16], wc_sel[16], red[16];
  const int b = blockIdx.x;
  const float* srow = scores + (size_t)b * S_;
  const int tid = threadIdx.x, lane = tid & 63, wid = tid >> 6;
  const float T = radix_select_T(srow, hist, &sh_b, &sh_gt, tid);

  int cgt = 0;
  #pragma unroll
  for (int c = 0; c < 8; ++c) cgt += (srow[c * 1024 + tid] > T) ? 1 : 0;
  cgt += __shfl_xor(cgt, 1);  cgt += __shfl_xor(cgt, 2);  cgt += __shfl_xor(cgt, 4);
  cgt += __shfl_xor(cgt, 8);  cgt += __shfl_xor(cgt, 16); cgt += __shfl_xor(cgt, 32);
  if (lane == 0) red[wid] = cgt;
  __syncthreads();
  int cnt_gt = 0;
  #pragma unroll
  for (int i = 0; i < 16; ++i) cnt_gt += red[i];
  const int need = CAP_ - cnt_gt;

  int* crow = comp + b * CAP_;
  int* urow = ucomp + b * UCAP_;
  int sel_base = 0, unsel_base = 0, eq_base = 0;
  __syncthreads();
  for (int c = 0; c < 8; ++c) {
    int idx = c * 1024 + tid;
    float s = srow[idx];
    bool gt = s > T, eq = (s == T);
    unsigned long long meq = __ballot(eq);
    if (lane == 0) wc_eq[wid] = __popcll(meq);
    __syncthreads();
    int eq_off = eq_base, eq_tot = 0;
    #pragma unroll
    for (int w2 = 0; w2 < 16; ++w2) { if (w2 < wid) eq_off += wc_eq[w2]; eq_tot += wc_eq[w2]; }
    int eqpos = eq_off + __popcll(meq & ((1ull << lane) - 1));
    bool take = gt || (eq && eqpos < need);
    unsigned long long mt = __ballot(take);
    if (lane == 0) wc_sel[wid] = __popcll(mt);
    __syncthreads();
    int sel_off = sel_base, sel_tot = 0;
    #pragma unroll
    for (int w2 = 0; w2 < 16; ++w2) { if (w2 < wid) sel_off += wc_sel[w2]; sel_tot += wc_sel[w2]; }
    if (take) {
      crow[sel_off + __popcll(mt & ((1ull << lane) - 1))] = idx;
    } else {
      int un_off = unsel_base + wid * 64 - (sel_off - sel_base);
      urow[un_off + __popcll(~mt & ((1ull << lane) - 1))] = idx;
    }
    sel_base += sel_tot; unsel_base += 1024 - sel_tot; eq_base += eq_tot;
    __syncthreads();
  }
}

// ---------------- fused gather(selected->xg bf16) + copy(unselected->out) ----
__global__ __launch_bounds__(256) void gather_copy_kernel(
    const float* __restrict__ x, const int* __restrict__ comp,
    const int* __restrict__ ucomp, unsigned short* __restrict__ xg,
    float* __restrict__ out) {
  const int bid = blockIdx.x;
  const int tx = threadIdx.x;
  if (bid < M_) {
    int b = bid >> 12, cc = bid & (CAP_ - 1);
    int token = comp[b * CAP_ + cc];
    float4 v = ((const float4*)(x + ((size_t)(b * S_ + token)) * H_))[tx];
    ushort4 o;
    o.x = f2bf(v.x); o.y = f2bf(v.y); o.z = f2bf(v.z); o.w = f2bf(v.w);
    *(ushort4*)&xg[(size_t)bid * H_ + tx * 4] = o;
  } else {
    int i = bid - M_;
    int b = i >> 12, r = i & (UCAP_ - 1);
    int token = ucomp[b * UCAP_ + r];
    size_t row = (size_t)b * S_ + token;
    ((float4*)(out + row * H_))[tx] = ((const float4*)(x + row * H_))[tx];
  }
}

// ---------------- main GEMM: 128x128 tile, 2-phase/K-tile, 2 blocks/CU -------
// 256 thr / 4 waves (2Mx2N, 64x64 per wave), BK=64, LDS 64.5KB.
// Waits derived: steady ph0-end vmcnt(4), ph1-end vmcnt(2); drain vmcnt(0).
#define MISSUE_A(U, KT, BUF) do {                                              \
    int c_i = (U) * 256 + t;                                                   \
    int row_ = c_i >> 3, sl_ = c_i & 7;                                        \
    int slz_ = sl_ ^ (row_ & 7);                                               \
    gload_lds16(xg + (size_t)(m0 + row_) * H_ + (KT) * 64 + slz_ * 8,          \
                &As[BUF][c_i * 8]);                                            \
  } while (0)
#define MISSUE_B(U, KT, BUF) do {                                              \
    int c_i = (U) * 256 + t;                                                   \
    int row_ = c_i >> 3, sl_ = c_i & 7;                                        \
    int slz_ = sl_ ^ (row_ & 7);                                               \
    gload_lds16(wlt + (size_t)(n0 + row_) * H_ + (KT) * 64 + slz_ * 8,         \
                &Bs[BUF][c_i * 8]);                                            \
  } while (0)
#define MPH(P, ISSUE, WAITCODE) do {                                           \
    s16x8 af[2][2];                                                            \
    _Pragma("unroll")                                                          \
    for (int i = 0; i < 2; ++i)                                                \
      _Pragma("unroll")                                                        \
      for (int kk = 0; kk < 2; ++kk) {                                         \
        int r_ = wr * 64 + ((P) * 2 + i) * 16 + r16;                           \
        af[i][kk] = *(const s16x8*)&As[c_][r_ * 64 + ((kk * 4 + ks) ^ (r_ & 7)) * 8]; \
      }                                                                        \
    if ((P) == 0) {                                                            \
      _Pragma("unroll")                                                        \
      for (int j = 0; j < 4; ++j)                                              \
        _Pragma("unroll")                                                      \
        for (int kk = 0; kk < 2; ++kk) {                                       \
          int r_ = wc * 64 + j * 16 + r16;                                     \
          bfr[j][kk] = *(const s16x8*)&Bs[c_][r_ * 64 + ((kk * 4 + ks) ^ (r_ & 7)) * 8]; \
        }                                                                      \
    }                                                                          \
    ISSUE                                                                      \
    __builtin_amdgcn_s_barrier();                                              \
    asm volatile("s_waitcnt lgkmcnt(0)" ::: "memory");                         \
    __builtin_amdgcn_sched_barrier(0);                                         \
    __builtin_amdgcn_s_setprio(1);                                             \
    _Pragma("unroll")                                                          \
    for (int i = 0; i < 2; ++i)                                                \
      _Pragma("unroll")                                                        \
      for (int j = 0; j < 4; ++j)                                              \
        _Pragma("unroll")                                                      \
        for (int kk = 0; kk < 2; ++kk)                                         \
          acc[(P) * 2 + i][j] = __builtin_amdgcn_mfma_f32_16x16x32_bf16(       \
              af[i][kk], bfr[j][kk], acc[(P) * 2 + i][j], 0, 0, 0);            \
    __builtin_amdgcn_s_setprio(0);                                             \
    __builtin_amdgcn_sched_barrier(0);                                         \
    WAITCODE                                                                   \
    __builtin_amdgcn_s_barrier();                                              \
    __builtin_amdgcn_sched_barrier(0);                                         \
  } while (0)

__global__ __launch_bounds__(256) void moe_gemm_kernel(
    const unsigned short* __restrict__ xg, const unsigned short* __restrict__ wlt,
    const int* __restrict__ comp, float* __restrict__ out) {
  __shared__ __align__(16) unsigned short As[2][128 * 64];
  __shared__ __align__(16) unsigned short Bs[2][128 * 64];
  __shared__ int toks[128];
  const int t = threadIdx.x;
  const int lane = t & 63, w = t >> 6;
  const int bid = blockIdx.x;
  const int xcd = bid & 7, r_ = bid >> 3;        // 256 units per XCD
  const int m0 = (xcd * 32 + (r_ >> 3)) * 128;   // 256 m-panels
  const int n0 = (r_ & 7) * 128;                 // 8 n-panels, n-fastest
  const int bb = m0 >> 12;
  if (t < 128) toks[t] = comp[bb * CAP_ + (m0 & (CAP_ - 1)) + t];
  const int wr = w >> 1, wc = w & 1;             // 2x2 wave grid, 64x64 each
  const int r16 = lane & 15, ks = lane >> 4;

  f32x4 acc[4][4];
  #pragma unroll
  for (int i = 0; i < 4; ++i)
    #pragma unroll
    for (int j = 0; j < 4; ++j) acc[i][j] = (f32x4){0.f, 0.f, 0.f, 0.f};

  // prologue: tile 0, issue order = consumption order (B0-3, A0,A2,A1,A3)
  MISSUE_B(0, 0, 0); MISSUE_B(1, 0, 0); MISSUE_B(2, 0, 0); MISSUE_B(3, 0, 0);
  MISSUE_A(0, 0, 0); MISSUE_A(2, 0, 0); MISSUE_A(1, 0, 0); MISSUE_A(3, 0, 0);
  asm volatile("s_waitcnt vmcnt(2)" ::: "memory");   // B0-3 + A0,A2 landed
  asm volatile("s_waitcnt lgkmcnt(0)" ::: "memory"); // toks ds_write visible
  __builtin_amdgcn_s_barrier();
  __builtin_amdgcn_sched_barrier(0);

  for (int kt = 0; kt < 15; ++kt) {
    const int c_ = kt & 1, nb_ = c_ ^ 1;
    const int kn = kt + 1;
    s16x8 bfr[4][2];
    MPH(0, { MISSUE_B(0, kn, nb_); MISSUE_B(1, kn, nb_);
             MISSUE_B(2, kn, nb_); MISSUE_B(3, kn, nb_); },
        { asm volatile("s_waitcnt vmcnt(4)" ::: "memory"); });
    MPH(1, { MISSUE_A(0, kn, nb_); MISSUE_A(2, kn, nb_);
             MISSUE_A(1, kn, nb_); MISSUE_A(3, kn, nb_); },
        { asm volatile("s_waitcnt vmcnt(2)" ::: "memory"); });
  }
  {  // kt = 15: drain
    const int c_ = 1;
    s16x8 bfr[4][2];
    MPH(0, {;}, { asm volatile("s_waitcnt vmcnt(0)" ::: "memory"); });
    MPH(1, {;}, {;});
  }

  // epilogue: gelu + scatter
  const int g4 = lane >> 4;
  #pragma unroll
  for (int i = 0; i < 4; ++i) {
    #pragma unroll
    for (int r = 0; r < 4; ++r) {
      int rl = wr * 64 + i * 16 + g4 * 4 + r;
      int token = toks[rl];
      float* orow = out + ((size_t)(bb * S_ + token)) * H_ + n0 + wc * 64;
      #pragma unroll
      for (int j = 0; j < 4; ++j)
        orow[j * 16 + r16] = gelu_f(acc[i][j][r]);
    }
  }
}

extern "C" void kernel_launch(void* const* d_in, const int* in_sizes, int n_in,
                              void* d_out, int out_size, void* d_ws, size_t ws_size,
                              hipStream_t stream) {
  const float* x  = (const float*)d_in[0];
  const float* W1 = (const float*)d_in[1];
  const float* b1 = (const float*)d_in[2];
  const float* W2 = (const float*)d_in[3];
  const float* b2 = (const float*)d_in[4];
  const float* Wl = (const float*)d_in[5];
  float* out = (float*)d_out;
  float* rw  = out + (size_t)B_ * S_ * H_;

  char* ws = (char*)d_ws;
  float* scores        = (float*)ws;                                 // 256 KB
  int*   comp          = (int*)(ws + (256 << 10));                   // 128 KB
  int*   count         = (int*)(ws + (384 << 10) + 256);             // 4 B
  int*   list          = (int*)(ws + (384 << 10) + 512);             // 32 KB
  int*   ucomp         = (int*)(ws + (448 << 10));                   // 128 KB
  unsigned short* wlt  = (unsigned short*)(ws + (1 << 20));          // 2 MB
  unsigned short* xg   = (unsigned short*)(ws + (3 << 20));          // 64 MB
  unsigned short* w1t_hi = xg;               // 512 KB (dead before xg written)

  hipLaunchKernelGGL(prep_kernel, dim3(1280), dim3(32, 8), 0, stream,
                     W1, w1t_hi, Wl, wlt);
  hipLaunchKernelGGL(router_mfma_kernel, dim3((B_*S_)/128), dim3(512), 0, stream,
                     x, w1t_hi, b1, W2, b2, scores, rw, count);
  hipLaunchKernelGGL(select_band_kernel, dim3(B_), dim3(1024), 0, stream,
                     scores, list, count);
  hipLaunchKernelGGL(recompute_kernel, dim3(128), dim3(256), 0, stream,
                     x, W1, b1, W2, b2, list, count, scores, rw);
  hipLaunchKernelGGL(compact_kernel, dim3(B_), dim3(1024), 0, stream,
                     scores, comp, ucomp);
  hipLaunchKernelGGL(gather_copy_kernel, dim3(M_ + B_*UCAP_), dim3(256), 0, stream,
                     x, comp, ucomp, xg, out);
  hipLaunchKernelGGL(moe_gemm_kernel, dim3((M_/128)*(H_/128)), dim3(256), 0, stream,
                     xg, wlt, comp, out);
}

// Round 20
// 362.918 us; speedup vs baseline: 1.1653x; 1.1525x over previous
//
#include <hip/hip_runtime.h>
#include <stdint.h>

#define B_   8
#define S_   8192
#define H_   1024
#define HQ_  256
#define CAP_ 4096
#define UCAP_ (S_-CAP_)
#define M_   (B_*CAP_)   // 32768
#define EPSB 0.012f
#define LCAP 8192

using f32x4 = __attribute__((ext_vector_type(4))) float;
using s16x8 = __attribute__((ext_vector_type(8))) short;

__device__ __forceinline__ unsigned short f2bf(float f) {
  unsigned u = __float_as_uint(f);
  u += 0x7FFF + ((u >> 16) & 1);   // RNE
  return (unsigned short)(u >> 16);
}
__device__ __forceinline__ float bf2f(unsigned short h) {
  return __uint_as_float(((unsigned)h) << 16);
}

// gelu tanh-approx via hw exp: 0.5v(1+tanh(z)) == v * sigmoid(2z)
__device__ __forceinline__ float gelu_f(float v) {
  float s = v + 0.044715f * v * v * v;
  float e = __expf(-1.5957691216057308f * s);
  return v * __builtin_amdgcn_rcpf(1.0f + e);
}

// monotonic fp32 <-> u32 key
__device__ __forceinline__ unsigned mono(float f) {
  unsigned u = __float_as_uint(f);
  return (u & 0x80000000u) ? ~u : (u | 0x80000000u);
}
__device__ __forceinline__ float unmono(unsigned k) {
  unsigned u = (k & 0x80000000u) ? (k & 0x7fffffffu) : ~k;
  return __uint_as_float(u);
}

__device__ __forceinline__ void gload_lds16(const void* g, void* l) {
  __builtin_amdgcn_global_load_lds(
      (const __attribute__((address_space(1))) void*)(uintptr_t)g,
      (__attribute__((address_space(3))) void*)(uintptr_t)l,
      16, 0, 0);
}

// in-block exact radix select: returns CAP_-th largest of srow[0..S_)
__device__ __forceinline__ float radix_select_T(
    const float* __restrict__ srow, unsigned* hist,
    unsigned* sh_b, unsigned* sh_gt, int tid) {
  unsigned prefix = 0; int plen = 0; unsigned rank = CAP_;
  #pragma unroll
  for (int round = 0; round < 3; ++round) {
    const int nb = (round < 2) ? 11 : 10;
    hist[tid] = 0; hist[tid + 1024] = 0;
    __syncthreads();
    for (int i = tid; i < S_; i += 1024) {
      unsigned k = mono(srow[i]);
      if (plen == 0 || (k >> (32 - plen)) == prefix) {
        unsigned bucket = (k << plen) >> (32 - nb);
        atomicAdd(&hist[bucket], 1u);
      }
    }
    __syncthreads();
    for (int s = 1; s < 2048; s <<= 1) {
      unsigned t0 = (tid + s < 2048) ? hist[tid + s] : 0;
      unsigned t1 = (tid + 1024 + s < 2048) ? hist[tid + 1024 + s] : 0;
      __syncthreads();
      hist[tid] += t0; hist[tid + 1024] += t1;
      __syncthreads();
    }
    #pragma unroll
    for (int h = 0; h < 2; ++h) {
      int i = tid + h * 1024;
      unsigned ge = hist[i];
      unsigned gt = (i < 2047) ? hist[i + 1] : 0;
      if (gt < rank && rank <= ge) { *sh_b = (unsigned)i; *sh_gt = gt; }
    }
    __syncthreads();
    prefix = (prefix << nb) | *sh_b;
    plen += nb;
    rank -= *sh_gt;
    __syncthreads();
  }
  return unmono(prefix);
}

// ---------------- fused prep: W1 -> w1t_hi (bf16 T) + Wl -> wlt (bf16 T) -----
__global__ __launch_bounds__(256) void prep_kernel(
    const float* __restrict__ W1, unsigned short* __restrict__ w1t_hi,
    const float* __restrict__ wl, unsigned short* __restrict__ wlt) {
  __shared__ float tile[32][33];
  const int bid = blockIdx.x;
  const int tx = threadIdx.x, ty = threadIdx.y;
  if (bid < 256) {
    int n0 = (bid & 7) * 32, k0 = (bid >> 3) * 32;
    for (int i = ty; i < 32; i += 8) tile[i][tx] = W1[(size_t)(k0 + i) * HQ_ + n0 + tx];
    __syncthreads();
    for (int i = ty; i < 32; i += 8)
      w1t_hi[(size_t)(n0 + i) * H_ + k0 + tx] = f2bf(tile[tx][i]);
  } else {
    int idx = bid - 256;
    int x0 = (idx & 31) * 32, y0 = (idx >> 5) * 32;
    for (int i = ty; i < 32; i += 8) tile[i][tx] = wl[(size_t)(y0 + i) * H_ + x0 + tx];
    __syncthreads();
    for (int i = ty; i < 32; i += 8)
      wlt[(size_t)(x0 + i) * H_ + y0 + tx] = f2bf(tile[tx][i]);
  }
}

// ---------------- Router GEMM: 128x256 tile, 4-phase, fp32-A in LDS ----------
#define RIA(U, KT, BUF) do {                                                   \
    int c_i = (U) * 512 + t;                                                   \
    int row_ = c_i >> 4, q_ = c_i & 15;                                        \
    int qz_ = q_ ^ (row_ & 15);                                                \
    gload_lds16(x + (size_t)(m0 + row_) * H_ + (KT) * 64 + qz_ * 4,            \
                &Af[BUF][(size_t)c_i * 4]);                                    \
  } while (0)
#define RIB(U, KT, BUF) do {                                                   \
    int row_ = (U) * 64 + (t >> 3);                                            \
    int sl_ = t & 7;                                                           \
    int slz_ = sl_ ^ (row_ & 7);                                               \
    gload_lds16(w1t_hi + (size_t)row_ * H_ + (KT) * 64 + slz_ * 8,             \
                &Bs[BUF][(size_t)row_ * 64 + sl_ * 8]);                        \
  } while (0)
#define RPH(P, ISSUE, WAITCODE) do {                                           \
    s16x8 af[2];                                                               \
    _Pragma("unroll")                                                          \
    for (int kk = 0; kk < 2; ++kk) {                                           \
      int r_ = wr * 64 + (P) * 16 + r16;                                       \
      int g2 = 2 * (kk * 4 + ks);                                              \
      float4 f0 = *(const float4*)&Af[c_][((size_t)r_ * 16 + (g2 ^ (r_ & 15))) * 4];       \
      float4 f1 = *(const float4*)&Af[c_][((size_t)r_ * 16 + ((g2 + 1) ^ (r_ & 15))) * 4]; \
      unsigned short hh[8];                                                    \
      hh[0] = f2bf(f0.x); hh[1] = f2bf(f0.y); hh[2] = f2bf(f0.z); hh[3] = f2bf(f0.w); \
      hh[4] = f2bf(f1.x); hh[5] = f2bf(f1.y); hh[6] = f2bf(f1.z); hh[7] = f2bf(f1.w); \
      af[kk] = *(s16x8*)hh;                                                    \
    }                                                                          \
    if ((P) == 0) {                                                            \
      _Pragma("unroll")                                                        \
      for (int j = 0; j < 4; ++j)                                              \
        _Pragma("unroll")                                                      \
        for (int kk = 0; kk < 2; ++kk) {                                       \
          int r_ = wc * 64 + j * 16 + r16;                                     \
          bfr[j][kk] = *(const s16x8*)&Bs[c_][(size_t)r_ * 64 + ((kk * 4 + ks) ^ (r_ & 7)) * 8]; \
        }                                                                      \
    }                                                                          \
    ISSUE                                                                      \
    __builtin_amdgcn_s_barrier();                                              \
    asm volatile("s_waitcnt lgkmcnt(0)" ::: "memory");                         \
    __builtin_amdgcn_sched_barrier(0);                                         \
    __builtin_amdgcn_s_setprio(1);                                             \
    _Pragma("unroll")                                                          \
    for (int j = 0; j < 4; ++j)                                                \
      _Pragma("unroll")                                                        \
      for (int kk = 0; kk < 2; ++kk)                                           \
        acc[P][j] = __builtin_amdgcn_mfma_f32_16x16x32_bf16(                   \
            af[kk], bfr[j][kk], acc[P][j], 0, 0, 0);                           \
    __builtin_amdgcn_s_setprio(0);                                             \
    __builtin_amdgcn_sched_barrier(0);                                         \
    WAITCODE                                                                   \
    __builtin_amdgcn_s_barrier();                                              \
    __builtin_amdgcn_sched_barrier(0);                                         \
  } while (0)

__global__ __launch_bounds__(512, 1) void router_mfma_kernel(
    const float* __restrict__ x, const unsigned short* __restrict__ w1t_hi,
    const float* __restrict__ b1, const float* __restrict__ W2,
    const float* __restrict__ b2, float* __restrict__ scores,
    float* __restrict__ rw, int* __restrict__ count) {
  __shared__ __align__(16) float Af[2][128 * 64];          // fp32 A, 2x32KB
  __shared__ __align__(16) unsigned short Bs[2][256 * 64]; // bf16 B, 2x32KB
  __shared__ float part[128][4];
  const int t = threadIdx.x;
  const int lane = t & 63, w = t >> 6;
  const int m0 = blockIdx.x * 128;
  if (blockIdx.x == 0 && t == 0) *count = 0;   // reset band counter
  const int wr = w >> 2, wc = w & 3;           // 2x4 wave grid, 64x64 each
  const int r16 = lane & 15, ks = lane >> 4;

  f32x4 acc[4][4];
  #pragma unroll
  for (int i = 0; i < 4; ++i)
    #pragma unroll
    for (int j = 0; j < 4; ++j) acc[i][j] = (f32x4){0.f, 0.f, 0.f, 0.f};

  // prologue: tile 0, order = consumption order (B0-3, A0, A2, A1, A3)
  RIB(0, 0, 0); RIB(1, 0, 0); RIB(2, 0, 0); RIB(3, 0, 0);
  RIA(0, 0, 0); RIA(2, 0, 0); RIA(1, 0, 0); RIA(3, 0, 0);
  asm volatile("s_waitcnt vmcnt(2)" ::: "memory");   // B0-3 + A0,A2 landed
  __syncthreads();

  for (int kt = 0; kt < 15; ++kt) {
    const int c_ = kt & 1, nb_ = c_ ^ 1;
    const int kn = kt + 1;
    s16x8 bfr[4][2];
    RPH(0, { RIB(0, kn, nb_); RIB(1, kn, nb_); }, {});
    RPH(1, { RIB(2, kn, nb_); RIB(3, kn, nb_); },
        { asm volatile("s_waitcnt vmcnt(4)" ::: "memory"); });
    RPH(2, { RIA(0, kn, nb_); RIA(2, kn, nb_); }, {});
    RPH(3, { RIA(1, kn, nb_); RIA(3, kn, nb_); },
        { asm volatile("s_waitcnt vmcnt(2)" ::: "memory"); });
  }
  {  // kt = 15: drain
    const int c_ = 1;
    s16x8 bfr[4][2];
    RPH(0, {;}, {});
    RPH(1, {;}, { asm volatile("s_waitcnt vmcnt(0)" ::: "memory"); });
    RPH(2, {;}, {});
    RPH(3, {;}, {});
  }

  // epilogue: relu(z+b1)*W2 partials, reduce across 4 wc groups
  float b1v[4], w2v[4];
  #pragma unroll
  for (int j = 0; j < 4; ++j) {
    int n = wc * 64 + j * 16 + r16;
    b1v[j] = b1[n]; w2v[j] = W2[n];
  }
  const int g4 = lane >> 4;
  #pragma unroll
  for (int i = 0; i < 4; ++i) {
    #pragma unroll
    for (int r = 0; r < 4; ++r) {
      float p = 0.f;
      #pragma unroll
      for (int j = 0; j < 4; ++j) {
        float h = acc[i][j][r] + b1v[j];
        h = fmaxf(h, 0.f);
        p = fmaf(h, w2v[j], p);
      }
      p += __shfl_xor(p, 1);
      p += __shfl_xor(p, 2);
      p += __shfl_xor(p, 4);
      p += __shfl_xor(p, 8);
      if (r16 == 0) part[wr * 64 + i * 16 + g4 * 4 + r][wc] = p;
    }
  }
  __syncthreads();
  if (t < 128) {
    float sc = part[t][0] + part[t][1] + part[t][2] + part[t][3] + b2[0];
    scores[m0 + t] = sc;
    rw[m0 + t] = 1.f / (1.f + expf(-sc));
  }
}

// ---------------- select + band (fused): T per row, then flag near-T tokens --
__global__ __launch_bounds__(1024) void select_band_kernel(
    const float* __restrict__ scores, int* __restrict__ list,
    int* __restrict__ count) {
  __shared__ unsigned hist[2048];
  __shared__ unsigned sh_b, sh_gt;
  const int b = blockIdx.x;
  const int tid = threadIdx.x;
  const float* srow = scores + (size_t)b * S_;
  const float T = radix_select_T(srow, hist, &sh_b, &sh_gt, tid);
  for (int i = tid; i < S_; i += 1024) {
    float s = srow[i];
    if (fabsf(s - T) <= EPSB) {
      int p = atomicAdd(count, 1);
      if (p < LCAP) list[p] = b * S_ + i;
    }
  }
}

// ---------------- exact fp32 recompute (scores + rw), 4 tokens/block ---------
__global__ __launch_bounds__(256) void recompute_kernel(
    const float* __restrict__ x, const float* __restrict__ W1,
    const float* __restrict__ b1, const float* __restrict__ W2,
    const float* __restrict__ b2, const int* __restrict__ list,
    const int* __restrict__ count, float* __restrict__ scores,
    float* __restrict__ rw) {
  __shared__ float xr[4][H_];
  __shared__ float red[4][4];
  int n = *count; if (n > LCAP) n = LCAP;
  const int j = threadIdx.x;
  for (int base = blockIdx.x * 4; base < n; base += gridDim.x * 4) {
    int nt = n - base; if (nt > 4) nt = 4;
    for (int tt = 0; tt < 4; ++tt) {
      int tok = list[base + ((tt < nt) ? tt : 0)];
      const float* xrow = x + (size_t)tok * H_;
      for (int k = j; k < H_; k += 256) xr[tt][k] = xrow[k];
    }
    __syncthreads();
    float a0 = 0.f, a1 = 0.f, a2 = 0.f, a3 = 0.f;
    for (int k = 0; k < H_; ++k) {
      float wv = W1[(size_t)k * HQ_ + j];
      a0 = fmaf(xr[0][k], wv, a0);
      a1 = fmaf(xr[1][k], wv, a1);
      a2 = fmaf(xr[2][k], wv, a2);
      a3 = fmaf(xr[3][k], wv, a3);
    }
    float aa[4] = {a0, a1, a2, a3};
    #pragma unroll
    for (int tt = 0; tt < 4; ++tt) {
      float h = fmaxf(aa[tt] + b1[j], 0.f);
      float v = h * W2[j];
      v += __shfl_xor(v, 1);  v += __shfl_xor(v, 2);  v += __shfl_xor(v, 4);
      v += __shfl_xor(v, 8);  v += __shfl_xor(v, 16); v += __shfl_xor(v, 32);
      if ((j & 63) == 0) red[tt][j >> 6] = v;
    }
    __syncthreads();
    if (j < nt) {
      int tok = list[base + j];
      float sc = red[j][0] + red[j][1] + red[j][2] + red[j][3] + b2[0];
      scores[tok] = sc;
      rw[tok] = 1.f / (1.f + expf(-sc));
    }
    __syncthreads();
  }
}

// ---------------- compact (fused radix): exact T then stable compaction ------
__global__ __launch_bounds__(1024) void compact_kernel(
    const float* __restrict__ scores, int* __restrict__ comp,
    int* __restrict__ ucomp) {
  __shared__ unsigned hist[2048];
  __shared__ unsigned sh_b, sh_gt;
  __shared__ int wc_eq[16], wc_sel[16], red[16];
  const int b = blockIdx.x;
  const float* srow = scores + (size_t)b * S_;
  const int tid = threadIdx.x, lane = tid & 63, wid = tid >> 6;
  const float T = radix_select_T(srow, hist, &sh_b, &sh_gt, tid);

  int cgt = 0;
  #pragma unroll
  for (int c = 0; c < 8; ++c) cgt += (srow[c * 1024 + tid] > T) ? 1 : 0;
  cgt += __shfl_xor(cgt, 1);  cgt += __shfl_xor(cgt, 2);  cgt += __shfl_xor(cgt, 4);
  cgt += __shfl_xor(cgt, 8);  cgt += __shfl_xor(cgt, 16); cgt += __shfl_xor(cgt, 32);
  if (lane == 0) red[wid] = cgt;
  __syncthreads();
  int cnt_gt = 0;
  #pragma unroll
  for (int i = 0; i < 16; ++i) cnt_gt += red[i];
  const int need = CAP_ - cnt_gt;

  int* crow = comp + b * CAP_;
  int* urow = ucomp + b * UCAP_;
  int sel_base = 0, unsel_base = 0, eq_base = 0;
  __syncthreads();
  for (int c = 0; c < 8; ++c) {
    int idx = c * 1024 + tid;
    float s = srow[idx];
    bool gt = s > T, eq = (s == T);
    unsigned long long meq = __ballot(eq);
    if (lane == 0) wc_eq[wid] = __popcll(meq);
    __syncthreads();
    int eq_off = eq_base, eq_tot = 0;
    #pragma unroll
    for (int w2 = 0; w2 < 16; ++w2) { if (w2 < wid) eq_off += wc_eq[w2]; eq_tot += wc_eq[w2]; }
    int eqpos = eq_off + __popcll(meq & ((1ull << lane) - 1));
    bool take = gt || (eq && eqpos < need);
    unsigned long long mt = __ballot(take);
    if (lane == 0) wc_sel[wid] = __popcll(mt);
    __syncthreads();
    int sel_off = sel_base, sel_tot = 0;
    #pragma unroll
    for (int w2 = 0; w2 < 16; ++w2) { if (w2 < wid) sel_off += wc_sel[w2]; sel_tot += wc_sel[w2]; }
    if (take) {
      crow[sel_off + __popcll(mt & ((1ull << lane) - 1))] = idx;
    } else {
      int un_off = unsel_base + wid * 64 - (sel_off - sel_base);
      urow[un_off + __popcll(~mt & ((1ull << lane) - 1))] = idx;
    }
    sel_base += sel_tot; unsel_base += 1024 - sel_tot; eq_base += eq_tot;
    __syncthreads();
  }
}

// ---------------- fused gather(selected->xg bf16) + copy(unselected->out) ----
__global__ __launch_bounds__(256) void gather_copy_kernel(
    const float* __restrict__ x, const int* __restrict__ comp,
    const int* __restrict__ ucomp, unsigned short* __restrict__ xg,
    float* __restrict__ out) {
  const int bid = blockIdx.x;
  const int tx = threadIdx.x;
  if (bid < M_) {
    int b = bid >> 12, cc = bid & (CAP_ - 1);
    int token = comp[b * CAP_ + cc];
    float4 v = ((const float4*)(x + ((size_t)(b * S_ + token)) * H_))[tx];
    ushort4 o;
    o.x = f2bf(v.x); o.y = f2bf(v.y); o.z = f2bf(v.z); o.w = f2bf(v.w);
    *(ushort4*)&xg[(size_t)bid * H_ + tx * 4] = o;
  } else {
    int i = bid - M_;
    int b = i >> 12, r = i & (UCAP_ - 1);
    int token = ucomp[b * UCAP_ + r];
    size_t row = (size_t)b * S_ + token;
    ((float4*)(out + row * H_))[tx] = ((const float4*)(x + row * H_))[tx];
  }
}

// ---------------- main GEMM: 256x256 tile, 4-phase/K-tile, counted vmcnt -----
#define ISSUE_A(P, KT, BUF) do {                                               \
    int row_ = half * 128 + (P) * 32 + rr;                                     \
    int slz_ = sl ^ (row_ & 7);                                                \
    gload_lds16(xg + (size_t)(m0 + row_) * H_ + (KT) * 64 + slz_ * 8,          \
                &As[BUF][row_ * 64 + sl * 8]);                                 \
  } while (0)
#define ISSUE_B(P, KT, BUF) do {                                               \
    int row_ = half * 128 + (P) * 32 + rr;                                     \
    int slz_ = sl ^ (row_ & 7);                                                \
    gload_lds16(wlt + (size_t)(n0 + row_) * H_ + (KT) * 64 + slz_ * 8,         \
                &Bs[BUF][row_ * 64 + sl * 8]);                                 \
  } while (0)
#define MOE_PHASE(P, ISSUE, WAITSTR) do {                                      \
    s16x8 af[2][2];                                                            \
    _Pragma("unroll")                                                          \
    for (int i = 0; i < 2; ++i)                                                \
      _Pragma("unroll")                                                        \
      for (int kk = 0; kk < 2; ++kk) {                                         \
        int r_ = wr * 128 + (2 * (P) + i) * 16 + r16;                          \
        af[i][kk] = *(const s16x8*)&As[c_][r_ * 64 + ((kk * 4 + ks) ^ (r_ & 7)) * 8]; \
      }                                                                        \
    if ((P) == 0) {                                                            \
      _Pragma("unroll")                                                        \
      for (int j = 0; j < 4; ++j)                                              \
        _Pragma("unroll")                                                      \
        for (int kk = 0; kk < 2; ++kk) {                                       \
          int r_ = wc * 64 + j * 16 + r16;                                     \
          bfr[j][kk] = *(const s16x8*)&Bs[c_][r_ * 64 + ((kk * 4 + ks) ^ (r_ & 7)) * 8]; \
        }                                                                      \
    }                                                                          \
    ISSUE                                                                      \
    __builtin_amdgcn_s_barrier();                                              \
    asm volatile("s_waitcnt lgkmcnt(0)" ::: "memory");                         \
    __builtin_amdgcn_sched_barrier(0);                                         \
    __builtin_amdgcn_s_setprio(1);                                             \
    _Pragma("unroll")                                                          \
    for (int i = 0; i < 2; ++i)                                                \
      _Pragma("unroll")                                                        \
      for (int j = 0; j < 4; ++j)                                              \
        _Pragma("unroll")                                                      \
        for (int kk = 0; kk < 2; ++kk)                                         \
          acc[2 * (P) + i][j] = __builtin_amdgcn_mfma_f32_16x16x32_bf16(       \
              af[i][kk], bfr[j][kk], acc[2 * (P) + i][j], 0, 0, 0);            \
    __builtin_amdgcn_s_setprio(0);                                             \
    __builtin_amdgcn_sched_barrier(0);                                         \
    asm volatile("s_waitcnt " WAITSTR ::: "memory");                           \
    __builtin_amdgcn_s_barrier();                                              \
    __builtin_amdgcn_sched_barrier(0);                                         \
  } while (0)

__global__ __launch_bounds__(512, 1) void moe_gemm_kernel(
    const unsigned short* __restrict__ xg, const unsigned short* __restrict__ wlt,
    const int* __restrict__ comp, float* __restrict__ out) {
  __shared__ __align__(16) unsigned short As[2][256 * 64];
  __shared__ __align__(16) unsigned short Bs[2][256 * 64];
  __shared__ int toks[256];
  const int t = threadIdx.x;
  const int lane = t & 63, w = t >> 6;
  const int bid = blockIdx.x;
  const int xcd = bid & 7, wb = bid >> 3;
  const int m0 = (xcd * 16 + (wb >> 2)) * 256;
  const int n0 = (wb & 3) * 256;
  const int bb = m0 >> 12;
  if (t < 256) toks[t] = comp[bb * CAP_ + (m0 & (CAP_ - 1)) + t];
  const int wr = w >> 2, wc = w & 3;
  const int r16 = lane & 15, ks = lane >> 4;
  const int half = t >> 8, rr = (t >> 3) & 31, sl = t & 7;

  f32x4 acc[8][4];
  #pragma unroll
  for (int i = 0; i < 8; ++i)
    #pragma unroll
    for (int j = 0; j < 4; ++j) acc[i][j] = (f32x4){0.f, 0.f, 0.f, 0.f};

  ISSUE_B(0, 0, 0); ISSUE_B(1, 0, 0); ISSUE_B(2, 0, 0); ISSUE_B(3, 0, 0);
  ISSUE_A(0, 0, 0); ISSUE_A(1, 0, 0); ISSUE_A(2, 0, 0); ISSUE_A(3, 0, 0);
  asm volatile("s_waitcnt vmcnt(3)" ::: "memory");
  __syncthreads();

  for (int kt = 0; kt < 15; ++kt) {
    const int c_ = kt & 1, nb_ = c_ ^ 1;
    const int kn = kt + 1;
    s16x8 bfr[4][2];
    MOE_PHASE(0, { ISSUE_B(0, kn, nb_); ISSUE_B(1, kn, nb_); }, "vmcnt(4)");
    MOE_PHASE(1, { ISSUE_B(2, kn, nb_); ISSUE_B(3, kn, nb_); }, "vmcnt(5)");
    MOE_PHASE(2, { ISSUE_A(0, kn, nb_); ISSUE_A(1, kn, nb_); }, "vmcnt(6)");
    MOE_PHASE(3, { ISSUE_A(2, kn, nb_); ISSUE_A(3, kn, nb_); }, "vmcnt(3)");
  }
  {
    const int c_ = 1;
    s16x8 bfr[4][2];
    MOE_PHASE(0, {;}, "vmcnt(2)");
    MOE_PHASE(1, {;}, "vmcnt(1)");
    MOE_PHASE(2, {;}, "vmcnt(0)");
    MOE_PHASE(3, {;}, "vmcnt(63)");
  }

  const int g4 = lane >> 4;
  #pragma unroll
  for (int i = 0; i < 8; ++i) {
    #pragma unroll
    for (int r = 0; r < 4; ++r) {
      int rl = wr * 128 + i * 16 + g4 * 4 + r;
      int token = toks[rl];
      float* orow = out + ((size_t)(bb * S_ + token)) * H_ + n0 + wc * 64;
      #pragma unroll
      for (int j = 0; j < 4; ++j)
        orow[j * 16 + r16] = gelu_f(acc[i][j][r]);
    }
  }
}

extern "C" void kernel_launch(void* const* d_in, const int* in_sizes, int n_in,
                              void* d_out, int out_size, void* d_ws, size_t ws_size,
                              hipStream_t stream) {
  const float* x  = (const float*)d_in[0];
  const float* W1 = (const float*)d_in[1];
  const float* b1 = (const float*)d_in[2];
  const float* W2 = (const float*)d_in[3];
  const float* b2 = (const float*)d_in[4];
  const float* Wl = (const float*)d_in[5];
  float* out = (float*)d_out;
  float* rw  = out + (size_t)B_ * S_ * H_;

  char* ws = (char*)d_ws;
  float* scores        = (float*)ws;                                 // 256 KB
  int*   comp          = (int*)(ws + (256 << 10));                   // 128 KB
  int*   count         = (int*)(ws + (384 << 10) + 256);             // 4 B
  int*   list          = (int*)(ws + (384 << 10) + 512);             // 32 KB
  int*   ucomp         = (int*)(ws + (448 << 10));                   // 128 KB
  unsigned short* wlt  = (unsigned short*)(ws + (1 << 20));          // 2 MB
  unsigned short* xg   = (unsigned short*)(ws + (3 << 20));          // 64 MB
  unsigned short* w1t_hi = xg;               // 512 KB (dead before xg written)

  hipLaunchKernelGGL(prep_kernel, dim3(1280), dim3(32, 8), 0, stream,
                     W1, w1t_hi, Wl, wlt);
  hipLaunchKernelGGL(router_mfma_kernel, dim3((B_*S_)/128), dim3(512), 0, stream,
                     x, w1t_hi, b1, W2, b2, scores, rw, count);
  hipLaunchKernelGGL(select_band_kernel, dim3(B_), dim3(1024), 0, stream,
                     scores, list, count);
  hipLaunchKernelGGL(recompute_kernel, dim3(256), dim3(256), 0, stream,
                     x, W1, b1, W2, b2, list, count, scores, rw);
  hipLaunchKernelGGL(compact_kernel, dim3(B_), dim3(1024), 0, stream,
                     scores, comp, ucomp);
  hipLaunchKernelGGL(gather_copy_kernel, dim3(M_ + B_*UCAP_), dim3(256), 0, stream,
                     x, comp, ucomp, xg, out);
  hipLaunchKernelGGL(moe_gemm_kernel, dim3((M_/256)*(H_/256)), dim3(512), 0, stream,
                     xg, wlt, comp, out);
}